// Round 7
// baseline (19.025 us; speedup 1.0000x reference)
//
#include <hip/hip_runtime.h>
#include <math.h>

// Problem constants (fixed shapes from setup_inputs)
#define B_N    16
#define T_LEN  65536
#define D_N    9                 // HARMONIC_NUM + 1
#define CHUNK  512
#define NCH    (T_LEN / CHUNK)   // 128 chunks per batch

// Fixed-point phase: 1 revolution = 2^32. Per-step increment
// q = trunc(f0 * 2^32/16000). Integer wraparound == mod 1 (exact).
#define PHASE_SCALE 268435.456f  // 2^32 / 16000

#define AS1C(p) ((const __attribute__((address_space(1))) void*)(p))
#define AS3(p)  ((__attribute__((address_space(3))) void*)(p))

__device__ __forceinline__ unsigned int ph(float f) {
    return (unsigned int)(f * PHASE_SCALE);   // v_cvt_u32_f32 (trunc)
}

// ---------------------------------------------------------------------------
// Pass 1: per-(b,chunk) sum of the u32 phase increments (wraps == mod 1).
// grid = 512 blocks x 256 threads; each WAVE owns one 512-ts chunk
// (8 t/lane). u32 butterfly: 6 single-shuffle steps (vs 12 for double).
// ---------------------------------------------------------------------------
__global__ __launch_bounds__(256) void k_chunksum(const float* __restrict__ f0,
                                                  unsigned int* __restrict__ csum) {
    int tid  = threadIdx.x;
    int lane = tid & 63;
    int wid  = tid >> 6;
    int chunk = blockIdx.x * 4 + wid;       // 0..2047 global chunk id
    int b = chunk >> 7;
    int c = chunk & 127;
    int t = c * CHUNK + lane * 8;
    size_t bt = (size_t)b * T_LEN + t;

    const float4 a0 = *reinterpret_cast<const float4*>(f0 + bt);
    const float4 a1 = *reinterpret_cast<const float4*>(f0 + bt + 4);
    unsigned int s = ph(a0.x) + ph(a0.y) + ph(a0.z) + ph(a0.w)
                   + ph(a1.x) + ph(a1.y) + ph(a1.z) + ph(a1.w);

    #pragma unroll
    for (int off = 32; off >= 1; off >>= 1)
        s += __shfl_down(s, off, 64);

    if (lane == 0) csum[(size_t)b * NCH + c] = s;
}

// ---------------------------------------------------------------------------
// Pass 2 (main). Each WAVE owns one (b,chunk)=512 ts; lane owns 8 timesteps.
// Block = 2 waves (128 thr), LDS 36864 B (proven size) -> 4 blocks/CU,
// 8 waves/CU: in-flight bytes/CU unchanged, HBM stream still saturated.
// Structure identical to R6 (proven): f0+csum issued first (vmcnt FIFO),
// 18 x 1KB noise->LDS stages, u32 scan + prefix, noise-independent B-sum
// under the load shadow, vmcnt-staircase dot product, tanh epilogue.
// ---------------------------------------------------------------------------
#define WAITV(n) asm volatile("s_waitcnt vmcnt(" #n ")" ::: "memory")

// consume granule Q: 4 floats, flat idx 4Q+i -> (j=(4Q+i)/9, h=(4Q+i)%9)
#define CONS(Q) do {                                                        \
    float4 v4 = ldsw[18 * lane + (Q)];                                      \
    dacc[(4*(Q)+0)/9] = fmaf(wreg[(4*(Q)+0)%9], v4.x, dacc[(4*(Q)+0)/9]);   \
    dacc[(4*(Q)+1)/9] = fmaf(wreg[(4*(Q)+1)%9], v4.y, dacc[(4*(Q)+1)/9]);   \
    dacc[(4*(Q)+2)/9] = fmaf(wreg[(4*(Q)+2)%9], v4.z, dacc[(4*(Q)+2)/9]);   \
    dacc[(4*(Q)+3)/9] = fmaf(wreg[(4*(Q)+3)%9], v4.w, dacc[(4*(Q)+3)/9]);   \
} while (0)

__global__ __launch_bounds__(128, 2) void k_main(const float* __restrict__ f0,
                                                 const float* __restrict__ noise,
                                                 const float* __restrict__ W,
                                                 const float* __restrict__ bias,
                                                 const float* __restrict__ rinit,
                                                 const unsigned int* __restrict__ csum,
                                                 float* __restrict__ out) {
    __shared__ float4 ldsbuf[2 * 1152];     // 2 waves x 1152 granules = 36864 B
    int tid  = threadIdx.x;
    int lane = tid & 63;
    int wid  = tid >> 6;
    int chunk = blockIdx.x * 2 + wid;
    int b = chunk >> 7;
    int c = chunk & 127;
    int t = c * CHUNK + lane * 8;
    size_t bt = (size_t)b * T_LEN + t;

    // ---- issue the loads the PRE-WAIT compute depends on FIRST
    // (vmcnt FIFO: these retire before the 18 noise stages).
    const float4 a0 = *reinterpret_cast<const float4*>(f0 + bt);
    const float4 a1 = *reinterpret_cast<const float4*>(f0 + bt + 4);
    const uint2  cs2 = *reinterpret_cast<const uint2*>(csum + (size_t)b * NCH + lane * 2);

    // uniform operands -> scalar loads (readfirstlane makes b provably uniform)
    int bu = __builtin_amdgcn_readfirstlane(b);
    const float* ri = rinit + bu * D_N;
    float wreg[D_N], rireg[D_N];
    #pragma unroll
    for (int h = 0; h < D_N; ++h) { wreg[h] = W[h]; rireg[h] = ri[h]; }
    float bb = bias[0];

    __builtin_amdgcn_sched_barrier(0);

    // ---- noise -> LDS staging (18 x 1KB per wave), issued AFTER f0/csum.
    float4* ldsw = ldsbuf + wid * 1152;
    const float* nbase = noise + ((size_t)b * T_LEN + (size_t)c * CHUNK) * D_N;
    #pragma unroll
    for (int q = 0; q < 18; ++q) {
        const float* g = nbase + (size_t)(lane + 64 * q) * 4;
        __builtin_amdgcn_global_load_lds(AS1C(g), AS3(ldsw + q * 64), 16, 0, 0);
    }
    __builtin_amdgcn_sched_barrier(0);

    // ---- u32 intra-wave scan of phase increments (wrap == mod 1, exact).
    float f[8] = {a0.x, a0.y, a0.z, a0.w, a1.x, a1.y, a1.z, a1.w};
    unsigned int s[8];
    unsigned int run = 0u;
    #pragma unroll
    for (int j = 0; j < 8; ++j) {
        run += ph(f[j]);
        s[j] = run;
    }
    unsigned int incl = run;
    #pragma unroll
    for (int off = 1; off < 64; off <<= 1) {
        unsigned int n = __shfl_up(incl, off, 64);
        if (lane >= off) incl += n;
    }

    // ---- exclusive chunk prefix: lane l holds csum[b][2l..2l+1],
    // mask by global idx < c, u32 butterfly (wrap-safe).
    int e0 = lane * 2;
    unsigned int pre = (e0 + 0 < c ? cs2.x : 0u)
                     + (e0 + 1 < c ? cs2.y : 0u);
    #pragma unroll
    for (int off = 32; off >= 1; off >>= 1)
        pre += __shfl_xor(pre, off, 64);

    unsigned int base = pre + (incl - run);

    // per-timestep fundamental phase in [0,1), uv gates, noise amps.
    float fr[8], uvf[8], na[8];
    #pragma unroll
    for (int j = 0; j < 8; ++j) {
        fr[j] = (float)(base + s[j]) * (1.0f / 4294967296.0f);
        bool uv = f[j] > 0.0f;
        uvf[j] = uv ? 0.1f : 0.0f;                   // fold SINE_AMP into uv
        na[j]  = uv ? 0.003f : (float)(0.1 / 3.0);   // NOISE_STD : SINE_AMP/3
    }

    // ---- noise-INdependent harmonic sum B[j], fully under the load shadow.
    float B[8] = {0.f, 0.f, 0.f, 0.f, 0.f, 0.f, 0.f, 0.f};
    #pragma unroll
    for (int h = 0; h < D_N; ++h) {
        const float hf = (float)(h + 1);
        const float wh = wreg[h];
        const float rih = rireg[h];
        #pragma unroll
        for (int j = 0; j < 8; ++j) {
            float x  = fmaf(fr[j], hf, rih);               // phase*h + init
            float xf = __builtin_amdgcn_fractf(x);         // frac -> [0,1)
            float sn = __builtin_amdgcn_sinf(xf);          // sin(2*pi*xf)
            B[j] = fmaf(sn, wh, B[j]);
        }
    }

    // ---- noise-dependent dot D[j], vmcnt staircase per granule.
    float dacc[8] = {0.f, 0.f, 0.f, 0.f, 0.f, 0.f, 0.f, 0.f};
    WAITV(17); CONS(0);
    WAITV(16); CONS(1);
    WAITV(15); CONS(2);
    WAITV(14); CONS(3);
    WAITV(13); CONS(4);
    WAITV(12); CONS(5);
    WAITV(11); CONS(6);
    WAITV(10); CONS(7);
    WAITV(9);  CONS(8);
    WAITV(8);  CONS(9);
    WAITV(7);  CONS(10);
    WAITV(6);  CONS(11);
    WAITV(5);  CONS(12);
    WAITV(4);  CONS(13);
    WAITV(3);  CONS(14);
    WAITV(2);  CONS(15);
    WAITV(1);  CONS(16);
    WAITV(0);  CONS(17);

    // ---- epilogue: y = uvf*B + na*D + bias; tanh = 1 - 2/(exp(2y)+1)
    float o[8];
    #pragma unroll
    for (int j = 0; j < 8; ++j) {
        float y = fmaf(na[j], dacc[j], fmaf(uvf[j], B[j], bb));
        float e = __expf(2.0f * y);
        float r = __builtin_amdgcn_rcpf(e + 1.0f);
        o[j] = 1.0f - 2.0f * r;
    }
    *reinterpret_cast<float4*>(out + bt)     = make_float4(o[0], o[1], o[2], o[3]);
    *reinterpret_cast<float4*>(out + bt + 4) = make_float4(o[4], o[5], o[6], o[7]);
}

// ---------------------------------------------------------------------------
extern "C" void kernel_launch(void* const* d_in, const int* in_sizes, int n_in,
                              void* d_out, int out_size, void* d_ws, size_t ws_size,
                              hipStream_t stream) {
    const float* f0    = (const float*)d_in[0];
    const float* rinit = (const float*)d_in[1];
    const float* noise = (const float*)d_in[2];
    const float* W     = (const float*)d_in[3];
    const float* bias  = (const float*)d_in[4];
    float* out = (float*)d_out;

    // workspace: csum [16*128] u32
    unsigned int* csum = (unsigned int*)d_ws;

    k_chunksum<<<(B_N * NCH) / 4, 256, 0, stream>>>(f0, csum);
    k_main<<<(B_N * NCH) / 2, 128, 0, stream>>>(f0, noise, W, bias, rinit, csum, out);
}

// Round 9
// 18.394 us; speedup vs baseline: 1.0343x; 1.0343x over previous
//
#include <hip/hip_runtime.h>
#include <math.h>

// Problem constants (fixed shapes from setup_inputs)
#define B_N    16
#define T_LEN  65536
#define D_N    9                 // HARMONIC_NUM + 1
#define CHUNK  256
#define NCH    (T_LEN / CHUNK)   // 256 chunks per batch

#define RCP_SR (1.0f / 16000.0f)

#define AS1C(p) ((const __attribute__((address_space(1))) void*)(p))
#define AS3(p)  ((__attribute__((address_space(3))) void*)(p))

typedef float vfloat4 __attribute__((ext_vector_type(4)));  // clang vector
                                                            // (nontemporal-
                                                            // store legal)

// ---------------------------------------------------------------------------
// Pass 1: per-(b,chunk) sum of rad_1 = f0 * (1/16000), double accumulate,
// stored as float frac. Only harmonic 1 is scanned; others are derived as
// integer multiples (frac-preserving). Identical to the proven R6 version.
// grid = 1024 blocks x 256 threads; each WAVE owns one chunk (4 t/lane).
// ---------------------------------------------------------------------------
__global__ __launch_bounds__(256) void k_chunksum(const float* __restrict__ f0,
                                                  float* __restrict__ csum) {
    int tid  = threadIdx.x;
    int lane = tid & 63;
    int wid  = tid >> 6;
    int chunk = blockIdx.x * 4 + wid;       // 0..4095 global chunk id
    int b = chunk >> 8;
    int c = chunk & 255;
    int t = c * CHUNK + lane * 4;
    size_t bt = (size_t)b * T_LEN + t;

    const float4 fv = *reinterpret_cast<const float4*>(f0 + bt);
    double s = (double)(fv.x * RCP_SR) + (double)(fv.y * RCP_SR)
             + (double)(fv.z * RCP_SR) + (double)(fv.w * RCP_SR);

    #pragma unroll
    for (int off = 32; off >= 1; off >>= 1)
        s += __shfl_down(s, off, 64);

    if (lane == 0) {
        double fr = s - floor(s);
        csum[(size_t)b * NCH + c] = (float)fr;
    }
}

// ---------------------------------------------------------------------------
// Pass 2 (main). Per-wave code is BYTE-IDENTICAL to the best (R6, 17.896us)
// version; only the packing changed: 8 waves/block (512 thr), LDS 73728 B
// -> 2 blocks/CU -> SAME 16 waves/CU (R7 proved 8 waves/CU regresses),
// but 512 blocks instead of 1024 -> half the dispatch ramp on the serial
// path after the k_chunksum drain. Output uses non-temporal stores (written
// once, never re-read -> no L2 write-allocate).
// ---------------------------------------------------------------------------
#define WAITV(n) asm volatile("s_waitcnt vmcnt(" #n ")" ::: "memory")

// consume granule Q: 4 floats, flat noise index 4Q+i -> (j=(4Q+i)/9, h=(4Q+i)%9)
#define CONS(Q) do {                                                        \
    float4 v4 = ldsw[9 * lane + (Q)];                                       \
    dacc[(4*(Q)+0)/9] = fmaf(wreg[(4*(Q)+0)%9], v4.x, dacc[(4*(Q)+0)/9]);   \
    dacc[(4*(Q)+1)/9] = fmaf(wreg[(4*(Q)+1)%9], v4.y, dacc[(4*(Q)+1)/9]);   \
    dacc[(4*(Q)+2)/9] = fmaf(wreg[(4*(Q)+2)%9], v4.z, dacc[(4*(Q)+2)/9]);   \
    dacc[(4*(Q)+3)/9] = fmaf(wreg[(4*(Q)+3)%9], v4.w, dacc[(4*(Q)+3)/9]);   \
} while (0)

__global__ __launch_bounds__(512, 4) void k_main(const float* __restrict__ f0,
                                                 const float* __restrict__ noise,
                                                 const float* __restrict__ W,
                                                 const float* __restrict__ bias,
                                                 const float* __restrict__ rinit,
                                                 const float* __restrict__ csum,
                                                 float* __restrict__ out) {
    __shared__ float4 ldsbuf[8 * 576];      // 8 waves x 576 granules = 73728 B
    int tid  = threadIdx.x;
    int lane = tid & 63;
    int wid  = tid >> 6;
    int chunk = blockIdx.x * 8 + wid;       // 8 waves/block, 512 blocks
    int b = chunk >> 8;                     // 32 blocks/batch: no straddle
    int c = chunk & 255;
    int t = c * CHUNK + lane * 4;
    size_t bt = (size_t)b * T_LEN + t;

    // ---- issue the loads the PRE-WAIT compute depends on FIRST
    // (vmcnt FIFO: these retire before the 9 noise stages).
    const float4 fv  = *reinterpret_cast<const float4*>(f0 + bt);
    const float4 cs4 = *reinterpret_cast<const float4*>(csum + (size_t)b * NCH + lane * 4);

    // uniform operands -> scalar loads (readfirstlane makes b provably uniform)
    int bu = __builtin_amdgcn_readfirstlane(b);
    const float* ri = rinit + bu * D_N;
    float wreg[D_N], rireg[D_N];
    #pragma unroll
    for (int h = 0; h < D_N; ++h) { wreg[h] = W[h]; rireg[h] = ri[h]; }
    float bb = bias[0];

    __builtin_amdgcn_sched_barrier(0);

    // ---- noise -> LDS staging (9 x 1KB per wave), issued AFTER f0/csum.
    // Linear layout; per-lane readback granule (9*lane+q): bank pattern
    // 4(l+q)%32 == linear b128, measured 0 conflicts.
    float4* ldsw = ldsbuf + wid * 576;
    const float* nbase = noise + ((size_t)b * T_LEN + (size_t)c * CHUNK) * D_N;
    #pragma unroll
    for (int q = 0; q < 9; ++q) {
        const float* g = nbase + (size_t)(lane + 64 * q) * 4;
        __builtin_amdgcn_global_load_lds(AS1C(g), AS3(ldsw + q * 64), 16, 0, 0);
    }
    __builtin_amdgcn_sched_barrier(0);

    // ---- float intra-wave scan of fundamental phase increment.
    float f[4] = {fv.x, fv.y, fv.z, fv.w};
    float s[4];
    float run = 0.0f;
    #pragma unroll
    for (int j = 0; j < 4; ++j) {
        run += f[j] * RCP_SR;
        s[j] = run;
    }
    float incl = run;
    #pragma unroll
    for (int off = 1; off < 64; off <<= 1) {
        float n = __shfl_up(incl, off, 64);
        if (lane >= off) incl += n;
    }

    // ---- exclusive chunk prefix: lane l holds csum[b][4l..4l+3],
    // mask by global idx < c, butterfly-sum (float, magnitude <= 256).
    int e0 = lane * 4;
    float pre = (e0 + 0 < c ? cs4.x : 0.0f)
              + (e0 + 1 < c ? cs4.y : 0.0f)
              + (e0 + 2 < c ? cs4.z : 0.0f)
              + (e0 + 3 < c ? cs4.w : 0.0f);
    #pragma unroll
    for (int off = 32; off >= 1; off >>= 1)
        pre += __shfl_xor(pre, off, 64);

    float base = __builtin_amdgcn_fractf(pre) + (incl - run);

    // per-timestep fundamental phase in [0,1), uv gates, noise amps.
    float fr[4], uvf[4], na[4];
    #pragma unroll
    for (int j = 0; j < 4; ++j) {
        fr[j] = __builtin_amdgcn_fractf(base + s[j]);   // base+s[j] <= ~8
        bool uv = f[j] > 0.0f;
        uvf[j] = uv ? 0.1f : 0.0f;                   // fold SINE_AMP into uv
        na[j]  = uv ? 0.003f : (float)(0.1 / 3.0);   // NOISE_STD : SINE_AMP/3
    }

    // ---- noise-INdependent harmonic sum B[j], fully under the load shadow.
    float B[4] = {0.f, 0.f, 0.f, 0.f};
    #pragma unroll
    for (int h = 0; h < D_N; ++h) {
        const float hf = (float)(h + 1);
        const float wh = wreg[h];
        const float rih = rireg[h];
        #pragma unroll
        for (int j = 0; j < 4; ++j) {
            float x  = fmaf(fr[j], hf, rih);               // phase*h + init
            float xf = __builtin_amdgcn_fractf(x);         // frac -> [0,1)
            float sn = __builtin_amdgcn_sinf(xf);          // sin(2*pi*xf)
            B[j] = fmaf(sn, wh, B[j]);
        }
    }

    // ---- noise-dependent dot D[j], vmcnt staircase per granule.
    float dacc[4] = {0.f, 0.f, 0.f, 0.f};
    WAITV(8); CONS(0);
    WAITV(7); CONS(1);
    WAITV(6); CONS(2);
    WAITV(5); CONS(3);
    WAITV(4); CONS(4);
    WAITV(3); CONS(5);
    WAITV(2); CONS(6);
    WAITV(1); CONS(7);
    WAITV(0); CONS(8);

    // ---- epilogue: y = uvf*B + na*D + bias; tanh = 1 - 2/(exp(2y)+1)
    vfloat4 o;
    #pragma unroll
    for (int j = 0; j < 4; ++j) {
        float y = fmaf(na[j], dacc[j], fmaf(uvf[j], B[j], bb));
        float e = __expf(2.0f * y);
        float r = __builtin_amdgcn_rcpf(e + 1.0f);
        o[j] = 1.0f - 2.0f * r;
    }
    // write-once output: non-temporal store (no L2 write-allocate/RFO).
    // vfloat4 is a clang ext_vector_type -> legal builtin operand.
    __builtin_nontemporal_store(o, reinterpret_cast<vfloat4*>(out + bt));
}

// ---------------------------------------------------------------------------
extern "C" void kernel_launch(void* const* d_in, const int* in_sizes, int n_in,
                              void* d_out, int out_size, void* d_ws, size_t ws_size,
                              hipStream_t stream) {
    const float* f0    = (const float*)d_in[0];
    const float* rinit = (const float*)d_in[1];
    const float* noise = (const float*)d_in[2];
    const float* W     = (const float*)d_in[3];
    const float* bias  = (const float*)d_in[4];
    float* out = (float*)d_out;

    // workspace: csum [16*256] f32
    float* csum = (float*)d_ws;

    k_chunksum<<<(B_N * NCH) / 4, 256, 0, stream>>>(f0, csum);
    k_main<<<(B_N * NCH) / 8, 512, 0, stream>>>(f0, noise, W, bias, rinit, csum, out);
}

// Round 10
// 17.454 us; speedup vs baseline: 1.0900x; 1.0538x over previous
//
#include <hip/hip_runtime.h>
#include <math.h>

// Problem constants (fixed shapes from setup_inputs)
#define B_N    16
#define T_LEN  65536
#define D_N    9                 // HARMONIC_NUM + 1
#define CHUNK  256
#define NCH    (T_LEN / CHUNK)   // 256 chunks per batch

#define RCP_SR (1.0f / 16000.0f)

#define AS1C(p) ((const __attribute__((address_space(1))) void*)(p))
#define AS3(p)  ((__attribute__((address_space(3))) void*)(p))

// ---------------------------------------------------------------------------
// FINAL (best measured: 17.896us, R6). Structural ledger:
//  - LDS-coalesced noise staging + f0-before-noise issue order: -4us (R1/R3)
//  - single-kernel fusion (coop launch / acq-rel flags / value flags):
//    broken under graph capture / +402us / +17us  -> two kernels is optimal
//  - post-wait tail restructure + vmcnt staircase: neutral (compute hidden)
//  - 8 waves/CU (CHUNK=512): +1.1us; 8-wave blocks + NT stores: +0.5us
// Remaining gap to the ~7us streaming floor is fixed launch/drain overhead.
// ---------------------------------------------------------------------------

// Pass 1: per-(b,chunk) sum of rad_1 = f0 * (1/16000), double accumulate,
// stored as float frac. Only harmonic 1 is scanned; others are derived as
// integer multiples (frac-preserving).
// grid = 1024 blocks x 256 threads; each WAVE owns one chunk (4 t/lane).
__global__ __launch_bounds__(256) void k_chunksum(const float* __restrict__ f0,
                                                  float* __restrict__ csum) {
    int tid  = threadIdx.x;
    int lane = tid & 63;
    int wid  = tid >> 6;
    int chunk = blockIdx.x * 4 + wid;       // 0..4095 global chunk id
    int b = chunk >> 8;
    int c = chunk & 255;
    int t = c * CHUNK + lane * 4;
    size_t bt = (size_t)b * T_LEN + t;

    const float4 fv = *reinterpret_cast<const float4*>(f0 + bt);
    double s = (double)(fv.x * RCP_SR) + (double)(fv.y * RCP_SR)
             + (double)(fv.z * RCP_SR) + (double)(fv.w * RCP_SR);

    #pragma unroll
    for (int off = 32; off >= 1; off >>= 1)
        s += __shfl_down(s, off, 64);

    if (lane == 0) {
        double fr = s - floor(s);
        csum[(size_t)b * NCH + c] = (float)fr;
    }
}

// ---------------------------------------------------------------------------
// Pass 2 (main). Each WAVE owns one (b,chunk); lane owns 4 timesteps.
// out[j] = tanh( uvf[j]*B[j] + na[j]*D[j] + bias )
//   B[j] = sum_h sin(2pi*frac(fr[j]*h + ri_h)) * W_h   (noise-INdependent,
//          computed under the noise-load shadow)
//   D[j] = sum_h W_h * noise[j][h]                     (vmcnt staircase)
// Issue order f0, csum, n0..n8 (vmcnt FIFO: scan waits vmcnt(9+), noise
// stays in flight). grid = 1024 x 256; LDS 36.9KB -> 4 blocks/CU,
// 16 waves/CU (proven optimal vs 8: R7).
// ---------------------------------------------------------------------------
#define WAITV(n) asm volatile("s_waitcnt vmcnt(" #n ")" ::: "memory")

// consume granule Q: 4 floats, flat noise index 4Q+i -> (j=(4Q+i)/9, h=(4Q+i)%9)
#define CONS(Q) do {                                                        \
    float4 v4 = ldsw[9 * lane + (Q)];                                       \
    dacc[(4*(Q)+0)/9] = fmaf(wreg[(4*(Q)+0)%9], v4.x, dacc[(4*(Q)+0)/9]);   \
    dacc[(4*(Q)+1)/9] = fmaf(wreg[(4*(Q)+1)%9], v4.y, dacc[(4*(Q)+1)/9]);   \
    dacc[(4*(Q)+2)/9] = fmaf(wreg[(4*(Q)+2)%9], v4.z, dacc[(4*(Q)+2)/9]);   \
    dacc[(4*(Q)+3)/9] = fmaf(wreg[(4*(Q)+3)%9], v4.w, dacc[(4*(Q)+3)/9]);   \
} while (0)

__global__ __launch_bounds__(256, 4) void k_main(const float* __restrict__ f0,
                                                 const float* __restrict__ noise,
                                                 const float* __restrict__ W,
                                                 const float* __restrict__ bias,
                                                 const float* __restrict__ rinit,
                                                 const float* __restrict__ csum,
                                                 float* __restrict__ out) {
    __shared__ float4 ldsbuf[4 * 576];      // 4 waves x 576 granules = 36864 B
    int tid  = threadIdx.x;
    int lane = tid & 63;
    int wid  = tid >> 6;
    int chunk = blockIdx.x * 4 + wid;
    int b = chunk >> 8;
    int c = chunk & 255;
    int t = c * CHUNK + lane * 4;
    size_t bt = (size_t)b * T_LEN + t;

    // ---- issue the loads the PRE-WAIT compute depends on FIRST
    // (vmcnt FIFO: these retire before the 9 noise stages).
    const float4 fv  = *reinterpret_cast<const float4*>(f0 + bt);
    const float4 cs4 = *reinterpret_cast<const float4*>(csum + (size_t)b * NCH + lane * 4);

    // uniform operands -> scalar loads (readfirstlane makes b provably uniform)
    int bu = __builtin_amdgcn_readfirstlane(b);
    const float* ri = rinit + bu * D_N;
    float wreg[D_N], rireg[D_N];
    #pragma unroll
    for (int h = 0; h < D_N; ++h) { wreg[h] = W[h]; rireg[h] = ri[h]; }
    float bb = bias[0];

    __builtin_amdgcn_sched_barrier(0);

    // ---- noise -> LDS staging (9 x 1KB per wave), issued AFTER f0/csum.
    // Linear layout; per-lane readback granule (9*lane+q): bank pattern
    // 4(l+q)%32 == linear b128, measured 0 conflicts.
    float4* ldsw = ldsbuf + wid * 576;
    const float* nbase = noise + ((size_t)b * T_LEN + (size_t)c * CHUNK) * D_N;
    #pragma unroll
    for (int q = 0; q < 9; ++q) {
        const float* g = nbase + (size_t)(lane + 64 * q) * 4;
        __builtin_amdgcn_global_load_lds(AS1C(g), AS3(ldsw + q * 64), 16, 0, 0);
    }
    __builtin_amdgcn_sched_barrier(0);

    // ---- float intra-wave scan of fundamental phase increment.
    float f[4] = {fv.x, fv.y, fv.z, fv.w};
    float s[4];
    float run = 0.0f;
    #pragma unroll
    for (int j = 0; j < 4; ++j) {
        run += f[j] * RCP_SR;
        s[j] = run;
    }
    float incl = run;
    #pragma unroll
    for (int off = 1; off < 64; off <<= 1) {
        float n = __shfl_up(incl, off, 64);
        if (lane >= off) incl += n;
    }

    // ---- exclusive chunk prefix: lane l holds csum[b][4l..4l+3],
    // mask by global idx < c, butterfly-sum (float, magnitude <= 256).
    int e0 = lane * 4;
    float pre = (e0 + 0 < c ? cs4.x : 0.0f)
              + (e0 + 1 < c ? cs4.y : 0.0f)
              + (e0 + 2 < c ? cs4.z : 0.0f)
              + (e0 + 3 < c ? cs4.w : 0.0f);
    #pragma unroll
    for (int off = 32; off >= 1; off >>= 1)
        pre += __shfl_xor(pre, off, 64);

    float base = __builtin_amdgcn_fractf(pre) + (incl - run);

    // per-timestep fundamental phase in [0,1), uv gates, noise amps.
    float fr[4], uvf[4], na[4];
    #pragma unroll
    for (int j = 0; j < 4; ++j) {
        fr[j] = __builtin_amdgcn_fractf(base + s[j]);   // base+s[j] <= ~8
        bool uv = f[j] > 0.0f;
        uvf[j] = uv ? 0.1f : 0.0f;                   // fold SINE_AMP into uv
        na[j]  = uv ? 0.003f : (float)(0.1 / 3.0);   // NOISE_STD : SINE_AMP/3
    }

    // ---- noise-INdependent harmonic sum B[j], fully under the load shadow.
    float B[4] = {0.f, 0.f, 0.f, 0.f};
    #pragma unroll
    for (int h = 0; h < D_N; ++h) {
        const float hf = (float)(h + 1);
        const float wh = wreg[h];
        const float rih = rireg[h];
        #pragma unroll
        for (int j = 0; j < 4; ++j) {
            float x  = fmaf(fr[j], hf, rih);               // phase*h + init
            float xf = __builtin_amdgcn_fractf(x);         // frac -> [0,1)
            float sn = __builtin_amdgcn_sinf(xf);          // sin(2*pi*xf)
            B[j] = fmaf(sn, wh, B[j]);
        }
    }

    // ---- noise-dependent dot D[j], vmcnt staircase per granule.
    float dacc[4] = {0.f, 0.f, 0.f, 0.f};
    WAITV(8); CONS(0);
    WAITV(7); CONS(1);
    WAITV(6); CONS(2);
    WAITV(5); CONS(3);
    WAITV(4); CONS(4);
    WAITV(3); CONS(5);
    WAITV(2); CONS(6);
    WAITV(1); CONS(7);
    WAITV(0); CONS(8);

    // ---- epilogue: y = uvf*B + na*D + bias; tanh = 1 - 2/(exp(2y)+1)
    float4 o;
    #pragma unroll
    for (int j = 0; j < 4; ++j) {
        float y = fmaf(na[j], dacc[j], fmaf(uvf[j], B[j], bb));
        float e = __expf(2.0f * y);
        float r = __builtin_amdgcn_rcpf(e + 1.0f);
        float th = 1.0f - 2.0f * r;
        (&o.x)[j] = th;
    }
    *reinterpret_cast<float4*>(out + bt) = o;
}

// ---------------------------------------------------------------------------
extern "C" void kernel_launch(void* const* d_in, const int* in_sizes, int n_in,
                              void* d_out, int out_size, void* d_ws, size_t ws_size,
                              hipStream_t stream) {
    const float* f0    = (const float*)d_in[0];
    const float* rinit = (const float*)d_in[1];
    const float* noise = (const float*)d_in[2];
    const float* W     = (const float*)d_in[3];
    const float* bias  = (const float*)d_in[4];
    float* out = (float*)d_out;

    // workspace: csum [16*256] f32
    float* csum = (float*)d_ws;

    k_chunksum<<<(B_N * NCH) / 4, 256, 0, stream>>>(f0, csum);
    k_main<<<(B_N * NCH) / 4, 256, 0, stream>>>(f0, noise, W, bias, rinit, csum, out);
}